// Round 9
// baseline (72.122 us; speedup 1.0000x reference)
//
#include <hip/hip_runtime.h>

#define NSEG 128
#define SSTEPS 32
#define TDIM 32
#define NG 8               // exclusive banked accumulator copies = groups/block
#define DROWS 35           // rows: 0 cnt, 1 = s=-1 mass, 2..33 = s 0..31, 34 junk
#define SPB 8              // splits per segment
#define CSTR (DROWS * TDIM)   // 1120 floats per copy
#define THREADS 256

// ---------------- Kernel: per-(segment,split) tiles, fused epilogue ---------
// R9: wall-outlier + search-depth + prefetch polish on the R8 frame.
//   * Special-case boundary targets 0 and NSEG: previously target==0
//     (all 8 blocks of segment 0) and target==128 (b=127) ALWAYS fell
//     into the serial 18-round binary-search fallback (~3-5K cyc of
//     dependent loads) -- deterministic slowest-block outliers that set
//     the kernel wall (all 1024 blocks co-resident, wall = max block).
//   * 2-round 64-lane search (wave w handles target b+w): stride-32 probe
//     (span 2048) then stride-1 probe; boundary = A+1+popcll(m2). One
//     fewer dependent global round than the old 3-round halves scheme.
//   * 4-deep register prefetch over the xs slab (R8 exposed ~120cyc
//     ds_read latency per pair); branchless masked tails (dead lanes add
//     0.0f to row 1 -- exact).
//   * Keeps: coalesced burst staging, exclusive per-group copies, 2-tap
//     exact decomposition, branchless rounds, two-level parallel scan,
//     init overlapped with search, fused atomic epilogue.
__global__ __launch_bounds__(THREADS) void ect_kernel(
    const float* __restrict__ x,       // [N,3]
    const int*   __restrict__ idx,     // [N] int32 or int64 (N even; detected)
    const float* __restrict__ v,       // [3,32]
    const float* __restrict__ lin,     // [32]
    const int*   __restrict__ scale_p, // [1]
    float*       __restrict__ out,     // [NSEG,32,32], pre-zeroed
    int N)
{
    __shared__ float d[NG][DROWS][TDIM];   // 35840 B
    __shared__ float4 xs[NG][32];          // 4096 B burst slab / scan scratch
    __shared__ int s_bounds[2];            // total 39944 B -> 4 blocks/CU

    const int tid = threadIdx.x;
    const unsigned bx = blockIdx.x;
    const int b = bx >> 3;            // segment
    const int j = bx & (SPB - 1);     // split

    // ---- 2-round wave-parallel boundary search (waves 0,1) ----
    if (tid < 128) {
        const int w = tid >> 6;                  // wave 0 -> b, wave 1 -> b+1
        const int L = tid & 63;
        const int target = b + w;
        if (target == 0) {
            if (L == 0) s_bounds[0] = 0;         // no loads, no fallback
        } else if (target == NSEG) {
            if (L == 0) s_bounds[1] = N;
        } else {
            const int g0 = (int)(((long long)target * N) >> 7);  // *N/128 guess
            const int hi_last = idx[N - 1];      // ==0 iff int64 (N even)
            const bool is64 = (hi_last == 0);

            // round 1: stride 32, span [g0-1024, g0+992]
            const int p1 = g0 - 1024 + 32 * L;
            const int pc1 = min(max(p1, 0), N - 1);
            const int val = is64 ? idx[2 * pc1] : idx[pc1];
            const bool pred1 = (p1 < 0) ? true : ((p1 >= N) ? false : (val < target));
            const unsigned long long m1 = __ballot(pred1);

            if (m1 == 0ull || ~m1 == 0ull) {
                if (L == 0) {                    // rare fallback: serial search
                    int lo = 0, hi = N;
                    while (lo < hi) {
                        int mid = (lo + hi) >> 1;
                        int vv = is64 ? idx[2 * mid] : idx[mid];
                        if (vv < target) lo = mid + 1; else hi = mid;
                    }
                    s_bounds[w] = lo;
                }
            } else {
                // A = largest stride-32 sample with val<target
                const int A = g0 - 1024 + 32 * (63 - __builtin_clzll(m1));
                // round 2: stride 1 covers (A, A+64] >= the 32-wide gap
                const int p2 = A + 1 + L;
                const int pc2 = min(p2, N - 1);
                const int v2 = is64 ? idx[2 * pc2] : idx[pc2];
                const bool pred2 = (p2 >= N) ? false : (v2 < target);
                const unsigned long long m2 = __ballot(pred2);
                if (L == 0) s_bounds[w] = A + 1 + __popcll(m2);
            }
        }
    } else {
        // waves 2,3 zero-init the accumulators while waves 0,1 search
        float4* dz = (float4*)d;
        for (int i = tid - 128; i < NG * CSTR / 4; i += THREADS - 128)
            dz[i] = make_float4(0.f, 0.f, 0.f, 0.f);
    }

    const float lin0 = lin[0];
    const float step = lin[1] - lin0;
    const float inv_step = 1.0f / step;
    const float negl0 = -lin0 * inv_step;
    const float scale = (float)scale_p[0];
    const float zstep = scale * step;          // ~35.48

    const int t = tid & 31;
    const int g = tid >> 5;                    // group 0..7, exclusive copy g
    const float v0 = v[t], v1 = v[TDIM + t], v2 = v[2 * TDIM + t];
    float* dg = &d[g][0][t];                   // row stride = 32 floats

    __syncthreads();

    const int start = s_bounds[0], end = s_bounds[1];
    const int cnt_n = end - start;
    const int chunk = (cnt_n + SPB - 1) / SPB;
    const int k0 = start + j * chunk;
    const int k1 = min(k0 + chunk, end);

    // ---- contiguous per-group range; burst-stage + 4-wide prefetched rounds
    {
        const int span = k1 - k0;
        const int cg = (span > 0) ? ((span + NG - 1) >> 3) : 0;
        const int kg0 = k0 + g * cg;
        const int kg1 = min(kg0 + cg, k1);
        float4* xsg = &xs[g][0];
        float cnt = 0.f;                       // mass fully below s=0

        // branchless per-node weight computation (2-tap exact decomposition)
        auto wcalc = [&](const float4 c, const bool valid,
                         float& wA, float& wB, int& row) {
            const float nh = fmaf(c.x, v0, fmaf(c.y, v1, c.z * v2));
            const float u = fminf(fmaxf(fmaf(nh, inv_step, negl0), -2.0f), 34.0f);
            const float rf = rintf(u);         // r in [-2,34]
            const float E = __expf((rf - u) * zstep);   // |arg| <= 17.75
            const float a = E * __builtin_amdgcn_rcpf(1.0f + E);
            const bool lv = valid & (rf > -2.0f) & (rf < 32.0f);
            cnt += (valid & (rf <= -2.0f)) ? 1.0f : 0.0f;
            row = lv ? ((int)rf + 2) : 1;      // dead lanes: row 1, weight 0
            wA = lv ? a : 0.f;
            wB = lv ? (1.0f - a) : 0.f;
        };

        for (int kb = kg0; kb < kg1; kb += 32) {
            const int nb = min(32, kg1 - kb);
            if (t < nb) {
                const float* xp = x + (size_t)(kb + t) * 3;
                xsg[t] = make_float4(xp[0], xp[1], xp[2], 0.f);
            }
            // same-wave DS pipe is in-order: staging writes are ordered
            // before the broadcast reads below.
            float4 c0 = xsg[0];
            float4 c1 = xsg[min(1, nb - 1)];
            float4 c2 = xsg[min(2, nb - 1)];
            float4 c3 = xsg[min(3, nb - 1)];
            for (int r = 0; r < nb; r += 4) {
                // prefetch next quad before touching current (hides ds_read)
                const int rn = r + 4;
                const float4 n0 = xsg[min(rn,     nb - 1)];
                const float4 n1 = xsg[min(rn + 1, nb - 1)];
                const float4 n2 = xsg[min(rn + 2, nb - 1)];
                const float4 n3 = xsg[min(rn + 3, nb - 1)];

                float wA0, wB0, wA1, wB1, wA2, wB2, wA3, wB3;
                int row0, row1, row2, row3;
                wcalc(c0, r + 0 < nb, wA0, wB0, row0);
                wcalc(c1, r + 1 < nb, wA1, wB1, row1);
                wcalc(c2, r + 2 < nb, wA2, wB2, row2);
                wcalc(c3, r + 3 < nb, wA3, wB3, row3);

                // sequential RMW pairs (rows may alias; in-order DS pipe
                // keeps same-address read-after-write correct)
                { float* p = dg + row0 * 32; const float a0 = p[0], a1 = p[32];
                  p[0] = a0 + wA0; p[32] = a1 + wB0; }
                { float* p = dg + row1 * 32; const float a0 = p[0], a1 = p[32];
                  p[0] = a0 + wA1; p[32] = a1 + wB1; }
                { float* p = dg + row2 * 32; const float a0 = p[0], a1 = p[32];
                  p[0] = a0 + wA2; p[32] = a1 + wB2; }
                { float* p = dg + row3 * 32; const float a0 = p[0], a1 = p[32];
                  p[0] = a0 + wA3; p[32] = a1 + wB3; }

                c0 = n0; c1 = n1; c2 = n2; c3 = n3;
            }
        }
        dg[0] = cnt;   // row 0 is exclusively the below-range counter row
    }
    __syncthreads();

    // fold copies 1..7 into copy 0 (float4): CSTR/4 = 280 quads
    {
        float4* c0 = (float4*)d;
        for (int i = tid; i < CSTR / 4; i += THREADS) {
            float4 a = c0[i];
            #pragma unroll
            for (int gg = 1; gg < NG; ++gg) {
                const float4 bq = ((const float4*)((const float*)d + gg * CSTR))[i];
                a.x += bq.x; a.y += bq.y; a.z += bq.z; a.w += bq.w;
            }
            c0[i] = a;
        }
    }
    __syncthreads();

    // ---- two-level parallel prefix over s (rows 2..33), all 256 lanes ----
    // worker (rb=tid>>5, t) owns rows 2+4rb .. 5+4rb; xs slab reused as scratch.
    {
        float* df = (float*)d;
        float* sums = (float*)xs;              // xs dead after main loop
        const int rb = tid >> 5;               // 0..7
        const int rowb = 2 + rb * 4;
        float w0 = df[(rowb + 0) * 32 + t];
        float w1 = df[(rowb + 1) * 32 + t];
        float w2 = df[(rowb + 2) * 32 + t];
        float w3 = df[(rowb + 3) * 32 + t];
        w1 += w0; w2 += w1; w3 += w2;          // local inclusive prefix
        sums[rb * 32 + t] = w3;
        __syncthreads();
        float off = df[t] + df[32 + t];        // below-range mass (rows 0,1)
        #pragma unroll
        for (int r = 0; r < 8; ++r) {
            const float sv = sums[r * 32 + t];
            off += (r < rb) ? sv : 0.f;
        }
        df[(rowb + 0) * 32 + t] = w0 + off;
        df[(rowb + 1) * 32 + t] = w1 + off;
        df[(rowb + 2) * 32 + t] = w2 + off;
        df[(rowb + 3) * 32 + t] = w3 + off;
    }
    __syncthreads();

    // fused reduction: atomicAdd tile into out (coalesced, 4 cells/thread);
    // stored rows 2..33 hold cumulative for s=0..31 -> offset +64 floats.
    {
        const float* df = (const float*)d;
        float* ob = out + (size_t)b * (SSTEPS * TDIM);
        #pragma unroll
        for (int q = 0; q < 4; ++q)
            atomicAdd(&ob[q * 256 + tid], df[64 + q * 256 + tid]);
    }
}

extern "C" void kernel_launch(void* const* d_in, const int* in_sizes, int n_in,
                              void* d_out, int out_size, void* d_ws, size_t ws_size,
                              hipStream_t stream) {
    const float* x     = (const float*)d_in[0];
    const int*   index = (const int*)d_in[1];
    const float* v     = (const float*)d_in[2];
    const float* lin   = (const float*)d_in[3];
    const int*   scale = (const int*)d_in[4];
    float* out = (float*)d_out;
    const int N = in_sizes[0] / 3;   // x is [N,3]

    hipMemsetAsync(d_out, 0, (size_t)out_size * sizeof(float), stream);
    ect_kernel<<<NSEG * SPB, THREADS, 0, stream>>>(x, index, v, lin, scale, out, N);
}